// Round 1
// baseline (932.160 us; speedup 1.0000x reference)
//
#include <hip/hip_runtime.h>
#include <cstdint>
#include <cmath>

#define B_SZ   2048
#define LE     100
#define LW     256
#define N_ENT  50000
#define N_WORD 30000
#define D      256
#define N_PAD  50048   /* 391 * 128 */
#define NT_N   391
#define NT_M   16

typedef unsigned short u16;
typedef short bf16x8 __attribute__((ext_vector_type(8)));
typedef float f32x4  __attribute__((ext_vector_type(4)));

__device__ __forceinline__ u16 f32_to_bf16(float f) {
  unsigned int x = __float_as_uint(f);
  unsigned int r = x + 0x7fffu + ((x >> 16) & 1u);   // RNE
  return (u16)(r >> 16);
}
__device__ __forceinline__ float bf16_to_f32(u16 u) {
  return __uint_as_float(((unsigned int)u) << 16);
}
__device__ __forceinline__ void async_copy16(void* lds, const void* g) {
  __builtin_amdgcn_global_load_lds((__attribute__((address_space(1))) void*)(g),
                                   (__attribute__((address_space(3))) void*)(lds),
                                   16, 0, 0);
}

// ---------------- kernel 0: v = w2 @ w1  (collapse the two gate linears), c = w2.b1 + b2
__global__ __launch_bounds__(512) void k_gatevec(const float* __restrict__ w1,
                                                 const float* __restrict__ b1,
                                                 const float* __restrict__ w2,
                                                 const float* __restrict__ b2,
                                                 float* __restrict__ v,
                                                 float* __restrict__ cscal) {
  int k = threadIdx.x;               // 0..511
  float acc = 0.f;
  for (int d = 0; d < D; ++d) acc += w2[d] * w1[d * (2 * D) + k];
  v[k] = acc;
  __shared__ float cred[D];
  if (k < D) cred[k] = w2[k] * b1[k];
  __syncthreads();
  if (k == 0) {
    float c = b2[0];
    for (int d = 0; d < D; ++d) c += cred[d];
    cscal[0] = c;
  }
}

// ---------------- kernel 1: entity_emb f32 -> bf16 hi/lo (padded to N_PAD rows)
__global__ __launch_bounds__(256) void k_split_ent(const float* __restrict__ ent,
                                                   u16* __restrict__ eh,
                                                   u16* __restrict__ el) {
  const long total4 = (long)N_PAD * (D / 4);
  const long valid4 = (long)N_ENT * (D / 4);
  long stride = (long)gridDim.x * blockDim.x;
  for (long i = (long)blockIdx.x * blockDim.x + threadIdx.x; i < total4; i += stride) {
    long e0 = i * 4;
    unsigned int h01 = 0, h23 = 0, l01 = 0, l23 = 0;
    if (i < valid4) {
      const float4 x = *(const float4*)(ent + e0);
      float xs[4] = {x.x, x.y, x.z, x.w};
      u16 hs[4], ls[4];
      for (int j = 0; j < 4; ++j) {
        hs[j] = f32_to_bf16(xs[j]);
        ls[j] = f32_to_bf16(xs[j] - bf16_to_f32(hs[j]));
      }
      h01 = (unsigned)hs[0] | ((unsigned)hs[1] << 16);
      h23 = (unsigned)hs[2] | ((unsigned)hs[3] << 16);
      l01 = (unsigned)ls[0] | ((unsigned)ls[1] << 16);
      l23 = (unsigned)ls[2] | ((unsigned)ls[3] << 16);
    }
    uint2 hv = make_uint2(h01, h23), lv = make_uint2(l01, l23);
    *(uint2*)(eh + e0) = hv;
    *(uint2*)(el + e0) = lv;
  }
}

// ---------------- kernel 2: gather means + fused gate + user -> bf16 hi/lo
__global__ __launch_bounds__(256) void k_user(const float* __restrict__ ent,
                                              const float* __restrict__ wrd,
                                              const int* __restrict__ rel_e,
                                              const int* __restrict__ rel_w,
                                              const float* __restrict__ v,
                                              const float* __restrict__ cscal,
                                              u16* __restrict__ uh,
                                              u16* __restrict__ ul) {
  __shared__ int   idxE[LE];
  __shared__ int   idxW[LW];
  __shared__ float4 redE[4][64];
  __shared__ float4 redW[4][64];
  __shared__ float gateSh;
  const int b = blockIdx.x, t = threadIdx.x;
  if (t < LE) idxE[t] = rel_e[b * LE + t];
  idxW[t] = rel_w[b * LW + t];
  __syncthreads();
  const int g = t >> 6, q = t & 63;
  float4 se = make_float4(0.f, 0.f, 0.f, 0.f);
  float4 sw = make_float4(0.f, 0.f, 0.f, 0.f);
  for (int l = g; l < LE; l += 4) {
    const float4 x = *(const float4*)(ent + (long)idxE[l] * D + q * 4);
    se.x += x.x; se.y += x.y; se.z += x.z; se.w += x.w;
  }
  for (int l = g; l < LW; l += 4) {
    const float4 x = *(const float4*)(wrd + (long)idxW[l] * D + q * 4);
    sw.x += x.x; sw.y += x.y; sw.z += x.z; sw.w += x.w;
  }
  redE[g][q] = se; redW[g][q] = sw;
  __syncthreads();
  float4 te = make_float4(0.f, 0.f, 0.f, 0.f);
  float4 tw = make_float4(0.f, 0.f, 0.f, 0.f);
  for (int gg = 0; gg < 4; ++gg) {
    te.x += redE[gg][q].x; te.y += redE[gg][q].y; te.z += redE[gg][q].z; te.w += redE[gg][q].w;
    tw.x += redW[gg][q].x; tw.y += redW[gg][q].y; tw.z += redW[gg][q].z; tw.w += redW[gg][q].w;
  }
  const float sclE = 1.f / (float)LE, sclW = 1.f / (float)LW;
  te.x *= sclE; te.y *= sclE; te.z *= sclE; te.w *= sclE;
  tw.x *= sclW; tw.y *= sclW; tw.z *= sclW; tw.w *= sclW;
  // gate logit partials (wave 0 holds the full q range)
  const float4 ve = *(const float4*)(v + q * 4);
  const float4 vw = *(const float4*)(v + D + q * 4);
  float p = te.x * ve.x + te.y * ve.y + te.z * ve.z + te.w * ve.w
          + tw.x * vw.x + tw.y * vw.y + tw.z * vw.z + tw.w * vw.w;
  if (g == 0) {
    float r = p;
    for (int off = 32; off; off >>= 1) r += __shfl_xor(r, off, 64);
    if (q == 0) {
      float logit = r + cscal[0];
      gateSh = 1.f / (1.f + expf(-logit));
    }
  }
  __syncthreads();
  const float gate = gateSh;
  if (g == 0) {
    float us[4] = {gate * te.x + (1.f - gate) * tw.x,
                   gate * te.y + (1.f - gate) * tw.y,
                   gate * te.z + (1.f - gate) * tw.z,
                   gate * te.w + (1.f - gate) * tw.w};
    u16 hs[4], ls[4];
    for (int j = 0; j < 4; ++j) {
      hs[j] = f32_to_bf16(us[j]);
      ls[j] = f32_to_bf16(us[j] - bf16_to_f32(hs[j]));
    }
    uint2 hv = make_uint2((unsigned)hs[0] | ((unsigned)hs[1] << 16),
                          (unsigned)hs[2] | ((unsigned)hs[3] << 16));
    uint2 lv = make_uint2((unsigned)ls[0] | ((unsigned)ls[1] << 16),
                          (unsigned)ls[2] | ((unsigned)ls[3] << 16));
    *(uint2*)(uh + (long)b * D + q * 4) = hv;
    *(uint2*)(ul + (long)b * D + q * 4) = lv;
  }
}

// ---------------- kernel 3: rec_scores = user @ entity_emb^T + bias (3-pass bf16 split MFMA)
__global__ __launch_bounds__(256) void k_gemm(const u16* __restrict__ uh, const u16* __restrict__ ul,
                                              const u16* __restrict__ eh, const u16* __restrict__ el,
                                              const float* __restrict__ rec_bias,
                                              float* __restrict__ out) {
  __shared__ u16 Ah[128 * 32], Al[128 * 32], Bh[128 * 32], Bl[128 * 32];
  const int bx = blockIdx.x;
  const int mt = bx & 15, nt = bx >> 4;         // m inner: consecutive blocks share B panel
  const int m0 = mt * 128, n0 = nt * 128;
  const int t = threadIdx.x;
  const int wv = t >> 6, lane = t & 63;
  const int wr = wv >> 1, wc = wv & 1;

  f32x4 acc[4][4];
  for (int i = 0; i < 4; ++i)
    for (int j = 0; j < 4; ++j) acc[i][j] = (f32x4){0.f, 0.f, 0.f, 0.f};

  for (int kk = 0; kk < 8; ++kk) {
    const int k0 = kk * 32;
    for (int c = 0; c < 2; ++c) {
      const int e0 = (c * 256 + t) * 8;
      const int r = e0 >> 5, col = e0 & 31;
      async_copy16(Ah + e0, uh + (long)(m0 + r) * D + k0 + col);
      async_copy16(Al + e0, ul + (long)(m0 + r) * D + k0 + col);
      async_copy16(Bh + e0, eh + (long)(n0 + r) * D + k0 + col);
      async_copy16(Bl + e0, el + (long)(n0 + r) * D + k0 + col);
    }
    __syncthreads();
    const int fr = lane & 15, koff = (lane >> 4) * 8;
    bf16x8 ah[4], al4[4], bh[4], bl4[4];
    for (int i = 0; i < 4; ++i) {
      const int ar = wr * 64 + i * 16 + fr;
      ah[i]  = *(const bf16x8*)(Ah + ar * 32 + koff);
      al4[i] = *(const bf16x8*)(Al + ar * 32 + koff);
      const int br = wc * 64 + i * 16 + fr;
      bh[i]  = *(const bf16x8*)(Bh + br * 32 + koff);
      bl4[i] = *(const bf16x8*)(Bl + br * 32 + koff);
    }
    for (int i = 0; i < 4; ++i)
      for (int j = 0; j < 4; ++j) {
        acc[i][j] = __builtin_amdgcn_mfma_f32_16x16x32_bf16(ah[i],  bh[j],  acc[i][j], 0, 0, 0);
        acc[i][j] = __builtin_amdgcn_mfma_f32_16x16x32_bf16(ah[i],  bl4[j], acc[i][j], 0, 0, 0);
        acc[i][j] = __builtin_amdgcn_mfma_f32_16x16x32_bf16(al4[i], bh[j],  acc[i][j], 0, 0, 0);
      }
    __syncthreads();
  }
  // epilogue: C/D layout col=lane&15, row=(lane>>4)*4+reg  [m89-verified]
  const int fr = lane & 15, fq = lane >> 4;
  for (int i = 0; i < 4; ++i)
    for (int j = 0; j < 4; ++j) {
      const int row0 = m0 + wr * 64 + i * 16 + fq * 4;
      const int n = n0 + wc * 64 + j * 16 + fr;
      if (n < N_ENT) {
        const float bias = rec_bias[n];
        for (int x = 0; x < 4; ++x)
          out[(size_t)(row0 + x) * N_ENT + n] = acc[i][j][x] + bias;
      }
    }
}

// ---------------- kernel 4: per-row online logsumexp -> per-row loss
__global__ __launch_bounds__(256) void k_loss(const float* __restrict__ scores,
                                              const int* __restrict__ labels,
                                              float* __restrict__ loss_rows) {
  const int b = blockIdx.x, t = threadIdx.x;
  const float* row = scores + (size_t)b * N_ENT;
  float m = -INFINITY, s = 0.f;
  for (int n = t; n < N_ENT; n += 256) {
    float x = row[n];
    float nm = fmaxf(m, x);
    s = s * expf(m - nm) + expf(x - nm);
    m = nm;
  }
  for (int off = 32; off; off >>= 1) {
    float om = __shfl_xor(m, off, 64);
    float os = __shfl_xor(s, off, 64);
    float nm = fmaxf(m, om);
    s = s * expf(m - nm) + os * expf(om - nm);
    m = nm;
  }
  __shared__ float ms[4], ss[4];
  const int wv = t >> 6, lane = t & 63;
  if (lane == 0) { ms[wv] = m; ss[wv] = s; }
  __syncthreads();
  if (t == 0) {
    float M = ms[0], S = ss[0];
    for (int w = 1; w < 4; ++w) {
      float nm = fmaxf(M, ms[w]);
      S = S * expf(M - nm) + ss[w] * expf(ms[w] - nm);
      M = nm;
    }
    loss_rows[b] = (M + logf(S)) - row[labels[b]];
  }
}

__global__ __launch_bounds__(256) void k_loss_final(const float* __restrict__ loss_rows,
                                                    float* __restrict__ out) {
  const int t = threadIdx.x;
  float s = 0.f;
  for (int i = t; i < B_SZ; i += 256) s += loss_rows[i];
  for (int off = 32; off; off >>= 1) s += __shfl_xor(s, off, 64);
  __shared__ float ws4[4];
  if ((t & 63) == 0) ws4[t >> 6] = s;
  __syncthreads();
  if (t == 0) out[(size_t)B_SZ * N_ENT] = (ws4[0] + ws4[1] + ws4[2] + ws4[3]) / (float)B_SZ;
}

extern "C" void kernel_launch(void* const* d_in, const int* in_sizes, int n_in,
                              void* d_out, int out_size, void* d_ws, size_t ws_size,
                              hipStream_t stream) {
  (void)in_sizes; (void)n_in; (void)out_size; (void)ws_size;
  const float* ent      = (const float*)d_in[0];
  const float* wrd      = (const float*)d_in[1];
  const float* w1       = (const float*)d_in[2];
  const float* b1       = (const float*)d_in[3];
  const float* w2       = (const float*)d_in[4];
  const float* b2       = (const float*)d_in[5];
  const float* rec_bias = (const float*)d_in[6];
  const int*   rel_e    = (const int*)d_in[7];
  const int*   rel_w    = (const int*)d_in[8];
  const int*   labels   = (const int*)d_in[9];
  float* out = (float*)d_out;

  char* ws = (char*)d_ws;
  float* v         = (float*)(ws);                       // 512 f32
  float* cscal     = (float*)(ws + 2048);                // 1 f32
  float* loss_rows = (float*)(ws + 4096);                // 2048 f32
  u16*   uh        = (u16*)(ws + 16384);                 // 2048*256 bf16
  u16*   ul        = (u16*)(ws + 16384 + 1048576);
  u16*   eh        = (u16*)(ws + 4194304);               // 50048*256 bf16
  u16*   el        = (u16*)(ws + 4194304 + 25624576);    // ends at ~55.4 MB

  k_split_ent<<<dim3(4096), dim3(256), 0, stream>>>(ent, eh, el);
  k_gatevec<<<dim3(1), dim3(512), 0, stream>>>(w1, b1, w2, b2, v, cscal);
  k_user<<<dim3(2048), dim3(256), 0, stream>>>(ent, wrd, rel_e, rel_w, v, cscal, uh, ul);
  k_gemm<<<dim3(NT_M * NT_N), dim3(256), 0, stream>>>(uh, ul, eh, el, rec_bias, out);
  k_loss<<<dim3(B_SZ), dim3(256), 0, stream>>>(out, labels, loss_rows);
  k_loss_final<<<dim3(1), dim3(256), 0, stream>>>(loss_rows, out);
}

// Round 2
// 726.065 us; speedup vs baseline: 1.2839x; 1.2839x over previous
//
#include <hip/hip_runtime.h>
#include <cstdint>
#include <cmath>

#define B_SZ   2048
#define LE     100
#define LW     256
#define N_ENT  50000
#define N_WORD 30000
#define D      256
#define N_PAD  50048   /* 391 * 128 */
#define NT_N   391
#define NT_M   16
#define NWG    (NT_M * NT_N)   /* 6256 = 8 * 782 */
#define NPT    (NT_N * 2)      /* 782 loss partials per row */

typedef unsigned short u16;
typedef _Float16 f16;
typedef f16   f16x8 __attribute__((ext_vector_type(8)));
typedef float f32x4 __attribute__((ext_vector_type(4)));

__device__ __forceinline__ float h2f(u16 x) { f16 h; __builtin_memcpy(&h, &x, 2); return (float)h; }
__device__ __forceinline__ u16   f2h(float x) { f16 h = (f16)x; u16 u; __builtin_memcpy(&u, &h, 2); return u; }
__device__ __forceinline__ void async_copy16(void* lds, const void* g) {
  __builtin_amdgcn_global_load_lds((__attribute__((address_space(1))) void*)(g),
                                   (__attribute__((address_space(3))) void*)(lds),
                                   16, 0, 0);
}

// ---------------- kernel 0: v = w2 @ w1 (collapse gate linears), c = w2.b1 + b2
__global__ __launch_bounds__(512) void k_gatevec(const float* __restrict__ w1,
                                                 const float* __restrict__ b1,
                                                 const float* __restrict__ w2,
                                                 const float* __restrict__ b2,
                                                 float* __restrict__ v,
                                                 float* __restrict__ cscal) {
  int k = threadIdx.x;
  float acc = 0.f;
#pragma unroll 8
  for (int d = 0; d < D; ++d) acc += w2[d] * w1[d * (2 * D) + k];
  v[k] = acc;
  __shared__ float cred[D];
  if (k < D) cred[k] = w2[k] * b1[k];
  __syncthreads();
  if (k == 0) {
    float c = b2[0];
    for (int d = 0; d < D; ++d) c += cred[d];
    cscal[0] = c;
  }
}

// ---------------- kernel 1: both tables f32 -> fp16 (entity padded to N_PAD rows)
__global__ __launch_bounds__(256) void k_cvt(const float* __restrict__ ent,
                                             const float* __restrict__ wrd,
                                             u16* __restrict__ eh,
                                             u16* __restrict__ wh) {
  const long totalE = (long)N_PAD * (D / 4);
  const long validE = (long)N_ENT * (D / 4);
  const long totalW = (long)N_WORD * (D / 4);
  const long total  = totalE + totalW;
  const long stride = (long)gridDim.x * blockDim.x;
  for (long i = (long)blockIdx.x * blockDim.x + threadIdx.x; i < total; i += stride) {
    float4 x = make_float4(0.f, 0.f, 0.f, 0.f);
    u16* dst; long e0;
    if (i < totalE) {
      e0 = i * 4;
      if (i < validE) x = *(const float4*)(ent + e0);
      dst = eh;
    } else {
      e0 = (i - totalE) * 4;
      x = *(const float4*)(wrd + e0);
      dst = wh;
    }
    ushort4 o;
    o.x = f2h(x.x); o.y = f2h(x.y); o.z = f2h(x.z); o.w = f2h(x.w);
    *(ushort4*)(dst + e0) = o;
  }
}

// ---------------- kernel 2: gather means (fp16 tables) + fused gate + user -> fp16
__global__ __launch_bounds__(256) void k_user(const u16* __restrict__ eh,
                                              const u16* __restrict__ wh,
                                              const int* __restrict__ rel_e,
                                              const int* __restrict__ rel_w,
                                              const float* __restrict__ v,
                                              const float* __restrict__ cscal,
                                              u16* __restrict__ uh) {
  __shared__ int    idxE[LE];
  __shared__ int    idxW[LW];
  __shared__ float4 redE[4][64];
  __shared__ float4 redW[4][64];
  __shared__ float  gateSh;
  const int b = blockIdx.x, t = threadIdx.x;
  if (t < LE) idxE[t] = rel_e[b * LE + t];
  idxW[t] = rel_w[b * LW + t];
  __syncthreads();
  const int g = t >> 6, q = t & 63;
  float4 se = make_float4(0.f, 0.f, 0.f, 0.f);
  float4 sw = make_float4(0.f, 0.f, 0.f, 0.f);
#pragma unroll 4
  for (int l = g; l < LE; l += 4) {
    const ushort4 u = *(const ushort4*)(eh + (long)idxE[l] * D + q * 4);
    se.x += h2f(u.x); se.y += h2f(u.y); se.z += h2f(u.z); se.w += h2f(u.w);
  }
#pragma unroll 4
  for (int l = g; l < LW; l += 4) {
    const ushort4 u = *(const ushort4*)(wh + (long)idxW[l] * D + q * 4);
    sw.x += h2f(u.x); sw.y += h2f(u.y); sw.z += h2f(u.z); sw.w += h2f(u.w);
  }
  redE[g][q] = se; redW[g][q] = sw;
  __syncthreads();
  float4 te = make_float4(0.f, 0.f, 0.f, 0.f);
  float4 tw = make_float4(0.f, 0.f, 0.f, 0.f);
  for (int gg = 0; gg < 4; ++gg) {
    te.x += redE[gg][q].x; te.y += redE[gg][q].y; te.z += redE[gg][q].z; te.w += redE[gg][q].w;
    tw.x += redW[gg][q].x; tw.y += redW[gg][q].y; tw.z += redW[gg][q].z; tw.w += redW[gg][q].w;
  }
  const float sclE = 1.f / (float)LE, sclW = 1.f / (float)LW;
  te.x *= sclE; te.y *= sclE; te.z *= sclE; te.w *= sclE;
  tw.x *= sclW; tw.y *= sclW; tw.z *= sclW; tw.w *= sclW;
  const float4 ve = *(const float4*)(v + q * 4);
  const float4 vw = *(const float4*)(v + D + q * 4);
  float p = te.x * ve.x + te.y * ve.y + te.z * ve.z + te.w * ve.w
          + tw.x * vw.x + tw.y * vw.y + tw.z * vw.z + tw.w * vw.w;
  if (g == 0) {
    float r = p;
    for (int off = 32; off; off >>= 1) r += __shfl_xor(r, off, 64);
    if (q == 0) {
      float logit = r + cscal[0];
      gateSh = 1.f / (1.f + expf(-logit));
    }
  }
  __syncthreads();
  const float gate = gateSh;
  if (g == 0) {
    ushort4 o;
    o.x = f2h(gate * te.x + (1.f - gate) * tw.x);
    o.y = f2h(gate * te.y + (1.f - gate) * tw.y);
    o.z = f2h(gate * te.z + (1.f - gate) * tw.z);
    o.w = f2h(gate * te.w + (1.f - gate) * tw.w);
    *(ushort4*)(uh + (long)b * D + q * 4) = o;
  }
}

// ---------------- kernel 3: scores = user @ ent^T + bias (fp16 1-pass MFMA)
//                 + fused per-(row, half-tile) online-softmax partials
__global__ __launch_bounds__(256) void k_gemm(const u16* __restrict__ uh,
                                              const u16* __restrict__ eh,
                                              const float* __restrict__ rec_bias,
                                              float* __restrict__ out,
                                              float* __restrict__ pmax,
                                              float* __restrict__ psum) {
  __shared__ u16 Ah[128 * 32], Bh[128 * 32];
  const int bx = blockIdx.x;
  const int wg = (bx & 7) * (NWG / 8) + (bx >> 3);   // XCD swizzle (6256 = 8*782)
  const int mt = wg & 15, nt = wg >> 4;              // m inner: blocks of one XCD share B panel
  const int m0 = mt * 128, n0 = nt * 128;
  const int t = threadIdx.x;
  const int wv = t >> 6, lane = t & 63;
  const int wr = wv >> 1, wc = wv & 1;
  const int fr = lane & 15, fq = lane >> 4;

  f32x4 acc[4][4];
  for (int i = 0; i < 4; ++i)
    for (int j = 0; j < 4; ++j) acc[i][j] = (f32x4){0.f, 0.f, 0.f, 0.f};

  for (int kk = 0; kk < 8; ++kk) {
    const int k0 = kk * 32;
#pragma unroll
    for (int c = 0; c < 2; ++c) {
      const int s = c * 256 + t;          // 16B slot id
      const int r = s >> 2, qs = s & 3;   // row, slot-in-row
      const int col = ((qs ^ ((r >> 1) & 3)) * 8);   // pre-swizzled source (T2, m173 pattern)
      async_copy16(Ah + s * 8, uh + (long)(m0 + r) * D + k0 + col);
      async_copy16(Bh + s * 8, eh + (long)(n0 + r) * D + k0 + col);
    }
    __syncthreads();
    f16x8 a[4], b[4];
#pragma unroll
    for (int i = 0; i < 4; ++i) {
      const int ar = wr * 64 + i * 16 + fr;
      a[i] = *(const f16x8*)(Ah + ar * 32 + ((fq ^ ((fr >> 1) & 3)) * 8));
      const int br = wc * 64 + i * 16 + fr;
      b[i] = *(const f16x8*)(Bh + br * 32 + ((fq ^ ((fr >> 1) & 3)) * 8));
    }
#pragma unroll
    for (int i = 0; i < 4; ++i)
#pragma unroll
      for (int j = 0; j < 4; ++j)
        acc[i][j] = __builtin_amdgcn_mfma_f32_16x16x32_f16(a[i], b[j], acc[i][j], 0, 0, 0);
    __syncthreads();
  }

  // epilogue: C/D layout col=lane&15, row=(lane>>4)*4+reg  [m89-verified]
  float bias[4]; bool valid[4]; int ncol[4];
#pragma unroll
  for (int j = 0; j < 4; ++j) {
    ncol[j] = n0 + wc * 64 + j * 16 + fr;
    valid[j] = ncol[j] < N_ENT;
    bias[j] = valid[j] ? rec_bias[ncol[j]] : 0.f;
  }
  const int pt = nt * 2 + wc;
#pragma unroll
  for (int i = 0; i < 4; ++i) {
    const int row0 = m0 + wr * 64 + i * 16 + fq * 4;
#pragma unroll
    for (int x = 0; x < 4; ++x) {
      float vals[4];
#pragma unroll
      for (int j = 0; j < 4; ++j)
        vals[j] = valid[j] ? acc[i][j][x] + bias[j] : -INFINITY;
#pragma unroll
      for (int j = 0; j < 4; ++j)
        if (valid[j]) out[(size_t)(row0 + x) * N_ENT + ncol[j]] = vals[j];
      // per-row online-softmax partial over this 64-col half-tile
      float mx = fmaxf(fmaxf(vals[0], vals[1]), fmaxf(vals[2], vals[3]));
#pragma unroll
      for (int off = 1; off < 16; off <<= 1) mx = fmaxf(mx, __shfl_xor(mx, off, 64));
      float sm = 0.f;
#pragma unroll
      for (int j = 0; j < 4; ++j)
        if (valid[j]) sm += __expf(vals[j] - mx);
#pragma unroll
      for (int off = 1; off < 16; off <<= 1) sm += __shfl_xor(sm, off, 64);
      if (fr == 0) {
        pmax[(size_t)pt * B_SZ + row0 + x] = mx;
        psum[(size_t)pt * B_SZ + row0 + x] = sm;
      }
    }
  }
}

// ---------------- kernel 4: combine loss partials -> per-row loss (coalesced [pt][row] reads)
__global__ __launch_bounds__(256) void k_loss_red(const float* __restrict__ pmax,
                                                  const float* __restrict__ psum,
                                                  const float* __restrict__ out,
                                                  const int* __restrict__ labels,
                                                  float* __restrict__ loss_rows) {
  const int r0 = blockIdx.x * 64;           // 32 blocks x 64 rows
  const int t = threadIdx.x, w = t >> 6, lane = t & 63;
  const int row = r0 + lane;
  float m = -INFINITY, s = 0.f;
  for (int pt = w; pt < NPT; pt += 4) {
    const float pm = pmax[(size_t)pt * B_SZ + row];
    const float ps = psum[(size_t)pt * B_SZ + row];
    const float nm = fmaxf(m, pm);
    s = s * __expf(m - nm) + ps * __expf(pm - nm);
    m = nm;
  }
  __shared__ float ms[4][64], ss[4][64];
  ms[w][lane] = m; ss[w][lane] = s;
  __syncthreads();
  if (t < 64) {
    float M = ms[0][lane], S = ss[0][lane];
    for (int ww = 1; ww < 4; ++ww) {
      const float pm = ms[ww][lane], ps = ss[ww][lane];
      const float nm = fmaxf(M, pm);
      S = S * __expf(M - nm) + ps * __expf(pm - nm);
      M = nm;
    }
    const float lse = M + logf(S);
    const int lab = labels[row];
    loss_rows[row] = lse - out[(size_t)row * N_ENT + lab];
  }
}

__global__ __launch_bounds__(256) void k_loss_final(const float* __restrict__ loss_rows,
                                                    float* __restrict__ out) {
  const int t = threadIdx.x;
  float s = 0.f;
  for (int i = t; i < B_SZ; i += 256) s += loss_rows[i];
  for (int off = 32; off; off >>= 1) s += __shfl_xor(s, off, 64);
  __shared__ float ws4[4];
  if ((t & 63) == 0) ws4[t >> 6] = s;
  __syncthreads();
  if (t == 0) out[(size_t)B_SZ * N_ENT] = (ws4[0] + ws4[1] + ws4[2] + ws4[3]) / (float)B_SZ;
}

extern "C" void kernel_launch(void* const* d_in, const int* in_sizes, int n_in,
                              void* d_out, int out_size, void* d_ws, size_t ws_size,
                              hipStream_t stream) {
  (void)in_sizes; (void)n_in; (void)out_size; (void)ws_size;
  const float* ent      = (const float*)d_in[0];
  const float* wrd      = (const float*)d_in[1];
  const float* w1       = (const float*)d_in[2];
  const float* b1       = (const float*)d_in[3];
  const float* w2       = (const float*)d_in[4];
  const float* b2       = (const float*)d_in[5];
  const float* rec_bias = (const float*)d_in[6];
  const int*   rel_e    = (const int*)d_in[7];
  const int*   rel_w    = (const int*)d_in[8];
  const int*   labels   = (const int*)d_in[9];
  float* out = (float*)d_out;

  char* ws = (char*)d_ws;
  float* v         = (float*)(ws);                    // 512 f32
  float* cscal     = (float*)(ws + 2048);             // 1 f32
  float* loss_rows = (float*)(ws + 4096);             // 2048 f32, ends 12288
  u16*   uh        = (u16*)(ws + 16384);              // 2048*256 fp16 = 1 MB
  float* pmax      = (float*)(ws + 1064960);          // 782*2048*4 = 6406144
  float* psum      = (float*)(ws + 7471104);          // 6406144
  u16*   eh        = (u16*)(ws + 13877248);           // 50048*256 fp16 = 25.6 MB
  u16*   wh        = (u16*)(ws + 39501824);           // 30000*256 fp16 = 15.4 MB, ends ~55.2 MB

  k_cvt<<<dim3(4096), dim3(256), 0, stream>>>(ent, wrd, eh, wh);
  k_gatevec<<<dim3(1), dim3(512), 0, stream>>>(w1, b1, w2, b2, v, cscal);
  k_user<<<dim3(B_SZ), dim3(256), 0, stream>>>(eh, wh, rel_e, rel_w, v, cscal, uh);
  k_gemm<<<dim3(NWG), dim3(256), 0, stream>>>(uh, eh, rec_bias, out, pmax, psum);
  k_loss_red<<<dim3(B_SZ / 64), dim3(256), 0, stream>>>(pmax, psum, out, labels, loss_rows);
  k_loss_final<<<dim3(1), dim3(256), 0, stream>>>(loss_rows, out);
}